// Round 14
// baseline (191.599 us; speedup 1.0000x reference)
//
#include <hip/hip_runtime.h>

// MHA forward, B=2, S=2048, D=1024, H=16, K=64, fp32 in/out, bf16 MFMA internally.
// R26 = R25 GEMMs/prep + attn back to R14 geometry (q-block 128, 2 qt/wave,
// 64KB LDS -> 2 WG/CU, grid 512) WITH the R17 XCD head-colocation swizzle.
// Theory: attn's stall is phase-lockstep (1 WG/CU = nothing to run at barrier
// drains; m114: co-resident blocks provide implicit pipelining). R14's 2-WG
// config lost pre-swizzle because HBM K/V re-fetch doubled (FETCH 70MB); with
// K/V L2-resident (12.35MB) that penalty is gone. Trade: +phase diversity vs
// -2x LDS reuse (~2us, R15). Swizzle: id = c + 8j; head_lin = c+8*(k&3),
// qx = k>>2 in [0,16). GEMMs 256x128 x 8 waves (R21/R22), prep unchanged.

#define NH 16
#define KS 64
#define DM 1024
#define BB 2
#define SS 2048
#define NT (BB*SS)   // 4096 tokens
#define HKD 1024     // NH*KS
#define L2E 1.44269504088896340736f

typedef __attribute__((ext_vector_type(4))) float floatx4;
typedef __attribute__((ext_vector_type(8))) short short8;

#define BAR() asm volatile("s_barrier" ::: "memory")

__device__ __forceinline__ unsigned short f2b(float f) {
  unsigned u = __builtin_bit_cast(unsigned, f);
  u = (u + 0x7fffu + ((u >> 16) & 1u)) >> 16;
  return (unsigned short)u;
}

__device__ __forceinline__ floatx4 mfma16(short8 a, short8 b, floatx4 c) {
  return __builtin_amdgcn_mfma_f32_16x16x32_bf16(a, b, c, 0, 0, 0);
}

// async global->LDS, 16B per lane. LDS dest must be wave-uniform base + lane*16.
__device__ __forceinline__ void async16(const void* g, void* l) {
  __builtin_amdgcn_global_load_lds(
      (const __attribute__((address_space(1))) unsigned int*)g,
      (__attribute__((address_space(3))) unsigned int*)l, 16, 0, 0);
}

// ------ prep: cast x (f32->bf16) + transpose+cast all W, one launch ------
__global__ __launch_bounds__(256) void prep_kernel(
    const float* __restrict__ x,
    const float* __restrict__ Wq, const float* __restrict__ Wk,
    const float* __restrict__ Wv, const float* __restrict__ Wo,
    unsigned short* __restrict__ xb,
    unsigned short* __restrict__ wqt, unsigned short* __restrict__ wkt,
    unsigned short* __restrict__ wvt, unsigned short* __restrict__ wot) {
  int bid = blockIdx.x;
  if (bid < NT * DM / 1024) {
    int i = (bid * 256 + threadIdx.x) * 4;
    float4 v = *(const float4*)(x + i);
    ushort4 o;
    o.x = f2b(v.x); o.y = f2b(v.y); o.z = f2b(v.z); o.w = f2b(v.w);
    *(ushort4*)(xb + i) = o;
    return;
  }
  int b2 = bid - NT * DM / 1024;
  int z = b2 >> 8;
  const float* W; unsigned short* Wt;
  if (z == 0)      { W = Wq; Wt = wqt; }
  else if (z == 1) { W = Wk; Wt = wkt; }
  else if (z == 2) { W = Wv; Wt = wvt; }
  else             { W = Wo; Wt = wot; }
  __shared__ __align__(16) unsigned short tile[64][80];
  int k0 = (b2 & 15) * 64, n0 = ((b2 >> 4) & 15) * 64;
  int t = threadIdx.x;
  int c0 = (t & 15) * 4, r = t >> 4;
  #pragma unroll
  for (int p = 0; p < 4; ++p) {
    int rr = r + p * 16;
    float4 v = *(const float4*)(W + (k0 + rr) * DM + n0 + c0);
    tile[c0 + 0][rr] = f2b(v.x);
    tile[c0 + 1][rr] = f2b(v.y);
    tile[c0 + 2][rr] = f2b(v.z);
    tile[c0 + 3][rr] = f2b(v.w);
  }
  __syncthreads();
  int cc0 = (t & 7) * 8, rn = t >> 3;
  #pragma unroll
  for (int p = 0; p < 2; ++p) {
    int nn = rn + p * 32;
    *(short8*)(Wt + (n0 + nn) * DM + k0 + cc0) = *(const short8*)(&tile[nn][cc0]);
  }
}

// ---- QKV GEMM: 256x128 tile, 8 waves, BK=32 dbuf + vmcnt(3) prefetch (R21) ----
__global__ __launch_bounds__(512) void gemm_qkv_kernel(
    const unsigned short* __restrict__ xb,
    const unsigned short* __restrict__ wqt, const unsigned short* __restrict__ wkt,
    const unsigned short* __restrict__ wvt,
    const float* __restrict__ bq, const float* __restrict__ bk, const float* __restrict__ bv,
    unsigned short* __restrict__ qb, unsigned short* __restrict__ kbuf,
    unsigned short* __restrict__ vt) {
  __shared__ __align__(16) unsigned short smem[24576]; // A [2][8192] | B @16384 [2][4096]
  // id = y + 8*(z + 3*x): y = XCD/B-panel class, z fastest within x -> A L2-hot x3
  int id = blockIdx.x;
  int y = id & 7, r2 = id >> 3;
  int zid = r2 % 3, xm = r2 / 3;
  const unsigned short* Bt; const float* bias; float scale;
  if (zid == 0)      { Bt = wqt; bias = bq; scale = 0.125f * L2E; }
  else if (zid == 1) { Bt = wkt; bias = bk; scale = 1.0f; }
  else               { Bt = wvt; bias = bv; scale = 1.0f; }
  int m0 = xm * 256, n0 = y * 128;
  int t = threadIdx.x, w = t >> 6, lane = t & 63, cl = lane & 15, quad = lane >> 4;
  int wr = (w >> 1) * 64, wc = (w & 1) * 64;
  floatx4 acc[4][4];
  #pragma unroll
  for (int i = 0; i < 4; ++i)
    #pragma unroll
    for (int j = 0; j < 4; ++j)
      acc[i][j] = floatx4{0.f, 0.f, 0.f, 0.f};

  auto stage = [&](int kc, int buf) {
    #pragma unroll
    for (int i = 0; i < 2; ++i) {
      int c = i * 512 + t;
      int row = c >> 2, col = (c & 3) ^ (row & 3);
      async16(xb + (m0 + row) * DM + kc * 32 + col * 8, &smem[buf * 8192 + c * 8]);
    }
    {
      int c = t;
      int row = c >> 2, col = (c & 3) ^ (row & 3);
      async16(Bt + (n0 + row) * DM + kc * 32 + col * 8, &smem[16384 + buf * 4096 + c * 8]);
    }
  };
  stage(0, 0);
  stage(1, 1);

  for (int kc = 0; kc < DM / 32; ++kc) {
    int cur = kc & 1;
    if (kc < DM / 32 - 1) asm volatile("s_waitcnt vmcnt(3)" ::: "memory");
    else                  asm volatile("s_waitcnt vmcnt(0)" ::: "memory");
    BAR();
    const unsigned short* Ac = &smem[cur * 8192];
    const unsigned short* Bc = &smem[16384 + cur * 4096];
    short8 a[4], b[4];
    #pragma unroll
    for (int i = 0; i < 4; ++i)
      a[i] = *(const short8*)&Ac[(wr + i * 16 + cl) * 32 + ((quad ^ (cl & 3)) * 8)];
    #pragma unroll
    for (int j = 0; j < 4; ++j)
      b[j] = *(const short8*)&Bc[(wc + j * 16 + cl) * 32 + ((quad ^ (cl & 3)) * 8)];
    #pragma unroll
    for (int i = 0; i < 4; ++i)
      #pragma unroll
      for (int j = 0; j < 4; ++j)
        acc[i][j] = mfma16(a[i], b[j], acc[i][j]);
    BAR();
    if (kc + 2 < DM / 32) stage(kc + 2, cur);
  }
  __syncthreads();

  int h = (n0 + wc) >> 6;
  if (zid < 2) {
    unsigned short* dst = (zid == 0) ? qb : kbuf;
    #pragma unroll
    for (int j = 0; j < 4; ++j) {
      float bj = bias[n0 + wc + j * 16 + cl];
      int kd = j * 16 + cl;
      #pragma unroll
      for (int i = 0; i < 4; ++i)
        #pragma unroll
        for (int r = 0; r < 4; ++r) {
          int token = m0 + wr + i * 16 + quad * 4 + r;
          int bz = token >> 11, s = token & (SS - 1);
          float val = (acc[i][j][r] + bj) * scale;
          dst[(((bz * NH + h) * SS + s) << 6) + kd] = f2b(val);
        }
    }
  } else {
    // V: transpose via per-wave LDS region, two rounds of 32 kd (8x2304 <= 24576)
    unsigned short* tr = &smem[w * 2304];
    int tokbase = m0 + wr;
    int bz = tokbase >> 11, s0 = tokbase & (SS - 1);
    unsigned short* vdst = vt + (((bz * NH + h) * KS) * SS) + s0;
    #pragma unroll
    for (int jr = 0; jr < 2; ++jr) {
      #pragma unroll
      for (int jj = 0; jj < 2; ++jj) {
        int j = jr * 2 + jj;
        float bj = bias[n0 + wc + j * 16 + cl];
        #pragma unroll
        for (int i = 0; i < 4; ++i) {
          unsigned short b0 = f2b(acc[i][j][0] + bj), b1 = f2b(acc[i][j][1] + bj);
          unsigned short b2 = f2b(acc[i][j][2] + bj), b3 = f2b(acc[i][j][3] + bj);
          uint2 pk;
          pk.x = (unsigned)b0 | ((unsigned)b1 << 16);
          pk.y = (unsigned)b2 | ((unsigned)b3 << 16);
          *(uint2*)&tr[(jj * 16 + cl) * 72 + i * 16 + quad * 4] = pk;
        }
      }
      asm volatile("s_waitcnt lgkmcnt(0)" ::: "memory");
      #pragma unroll
      for (int p = 0; p < 4; ++p) {
        int row = p * 8 + (lane >> 3);
        int tk = (lane & 7) * 8;
        short8 vv = *(const short8*)&tr[row * 72 + tk];
        *(short8*)(vdst + (jr * 32 + row) * SS + tk) = vv;
      }
    }
  }
}

// ---- attention: R14 geometry (q-block 128, 2 qt, 2 WG/CU) + XCD swizzle ----
// smem (shorts): K tiles [(st*3+buf)*2048], V tiles [12288+(st*3+buf)*2048],
// P per wave [24576 + w*1024]. 64 KB -> 2 WG/CU. Reduction reuses smem floats.
__global__ __launch_bounds__(512) void attn_kernel(
    const unsigned short* __restrict__ Q, const unsigned short* __restrict__ Kb,
    const unsigned short* __restrict__ Vt, unsigned short* __restrict__ AO) {
  __shared__ __align__(16) unsigned short smem[32768];
  int t = threadIdx.x, w = t >> 6, lane = t & 63, cl = lane & 15, quad = lane >> 4;
  int clm = cl & 7, cl3 = cl & 3, cl2 = cl >> 2;
  // XCD head-colocation: id = c + 8k; head_lin = c + 8*(k&3); qx = k>>2 in [0,16)
  int id = blockIdx.x + (SS / 128) * (blockIdx.y + NH * blockIdx.z);
  int c = id & 7, k = id >> 3;
  int head_lin = c + 8 * (k & 3);           // 0..31
  int qx = k >> 2;                          // 0..15
  int h = head_lin & (NH - 1), bz = head_lin >> 4;
  int bh = bz * NH + h;
  int slice = w & 3, part = w >> 2;
  int q0 = qx * 128 + slice * 32;
  const unsigned short* Qp = Q + (bh * SS + q0) * KS;
  const unsigned short* Kp = Kb + bh * SS * KS;
  const unsigned short* Vp = Vt + bh * KS * SS;
  unsigned short* p_w = smem + 24576 + w * 1024;

  short8 qa[2][2];
  #pragma unroll
  for (int qt = 0; qt < 2; ++qt)
    #pragma unroll
    for (int cc = 0; cc < 2; ++cc)
      qa[qt][cc] = *(const short8*)(Qp + (qt * 16 + cl) * KS + cc * 32 + quad * 8);

  short8 ones;
  #pragma unroll
  for (int j = 0; j < 8; ++j) ones[j] = (short)0x3f80; // bf16 1.0

  floatx4 lacc[2];
  floatx4 oa[2][4];
  #pragma unroll
  for (int qt = 0; qt < 2; ++qt) {
    lacc[qt] = floatx4{0.f, 0.f, 0.f, 0.f};
    #pragma unroll
    for (int j = 0; j < 4; ++j) oa[qt][j] = floatx4{0.f, 0.f, 0.f, 0.f};
  }

  int st = t >> 8, lt = t & 255;
  int krow = lt >> 3, kcol = (lt & 7) ^ (krow & 7);
  int vd = lt >> 2, vcol = ((lt & 3) ^ (vd & 3) ^ ((vd >> 2) & 3)) & 3;
  auto stage = [&](int it, int buf) {
    async16(Kp + (st * 1024 + it * 32 + krow) * KS + kcol * 8,
            &smem[(st * 3 + buf) * 2048 + lt * 8]);
    async16(Vp + vd * SS + st * 1024 + it * 32 + vcol * 8,
            &smem[12288 + (st * 3 + buf) * 2048 + lt * 8]);
  };
  stage(0, 0);
  stage(1, 1);

  const int NIT = 1024 / 32; // 32 tiles per part
  int cur = 0;
  for (int it = 0; it < NIT; ++it) {
    if (it < NIT - 1) asm volatile("s_waitcnt vmcnt(2)" ::: "memory");
    else              asm volatile("s_waitcnt vmcnt(0)" ::: "memory");
    BAR();
    if (it + 2 < NIT) {
      int sb = (cur >= 1) ? cur - 1 : 2; // (cur+2)%3
      stage(it + 2, sb);
    }
    const unsigned short* Kc = &smem[(part * 3 + cur) * 2048];
    const unsigned short* Vc = &smem[12288 + (part * 3 + cur) * 2048];

    floatx4 s[2][2];
    __builtin_amdgcn_s_setprio(1);
    #pragma unroll
    for (int kt = 0; kt < 2; ++kt) {
      short8 kb0 = *(const short8*)&Kc[(kt * 16 + cl) * 64 + ((quad ^ clm) * 8)];
      short8 kb1 = *(const short8*)&Kc[(kt * 16 + cl) * 64 + (((4 + quad) ^ clm) * 8)];
      #pragma unroll
      for (int qt = 0; qt < 2; ++qt) {
        floatx4 z = {0.f, 0.f, 0.f, 0.f};
        s[qt][kt] = mfma16(kb1, qa[qt][1], mfma16(kb0, qa[qt][0], z));
      }
    }
    __builtin_amdgcn_s_setprio(0);
    #pragma unroll
    for (int qt = 0; qt < 2; ++qt)
      #pragma unroll
      for (int kt = 0; kt < 2; ++kt) {
        unsigned u[4];
        #pragma unroll
        for (int r = 0; r < 4; ++r)
          u[r] = __builtin_bit_cast(unsigned, __builtin_amdgcn_exp2f(s[qt][kt][r]));
        uint2 pk;
        pk.x = __builtin_amdgcn_perm(u[1], u[0], 0x07060302);
        pk.y = __builtin_amdgcn_perm(u[3], u[2], 0x07060302);
        int blk = ((kt * 2 + (quad >> 1)) ^ cl3 ^ cl2) & 3;
        int off = qt * 512 + cl * 32 + blk * 8 + (quad & 1) * 4;
        *(uint2*)(p_w + off) = pk;
      }
    asm volatile("s_waitcnt lgkmcnt(0)" ::: "memory");
    short8 pa[2];
    __builtin_amdgcn_s_setprio(1);
    #pragma unroll
    for (int qt = 0; qt < 2; ++qt) {
      pa[qt] = *(const short8*)(p_w + qt * 512 + cl * 32 + (((quad ^ cl3 ^ cl2) & 3) * 8));
      lacc[qt] = mfma16(ones, pa[qt], lacc[qt]);
    }
    #pragma unroll
    for (int j = 0; j < 4; ++j) {
      short8 vb = *(const short8*)&Vc[(j * 16 + cl) * 32 + (((quad ^ cl3 ^ cl2) & 3) * 8)];
      #pragma unroll
      for (int qt = 0; qt < 2; ++qt)
        oa[qt][j] = mfma16(vb, pa[qt], oa[qt][j]);
    }
    __builtin_amdgcn_s_setprio(0);
    cur = (cur == 2) ? 0 : cur + 1;
  }

  // combine parts: part1 dumps (O, l) to LDS; part0 adds, normalizes, stores
  __syncthreads();
  float* red = (float*)smem;
  float* base = red + slice * 2304; // 4 slices x 9216B <= 64KB
  if (part == 1) {
    #pragma unroll
    for (int qt = 0; qt < 2; ++qt)
      #pragma unroll
      for (int j = 0; j < 4; ++j)
        *(floatx4*)(base + (((qt * 4 + j) * 64 + lane) << 2)) = oa[qt][j];
    base[2048 + lane * 2 + 0] = lacc[0][0];
    base[2048 + lane * 2 + 1] = lacc[1][0];
  }
  __syncthreads();
  if (part == 0) {
    #pragma unroll
    for (int qt = 0; qt < 2; ++qt)
      #pragma unroll
      for (int j = 0; j < 4; ++j)
        oa[qt][j] += *(const floatx4*)(base + (((qt * 4 + j) * 64 + lane) << 2));
    float lsum[2];
    lsum[0] = lacc[0][0] + base[2048 + lane * 2 + 0];
    lsum[1] = lacc[1][0] + base[2048 + lane * 2 + 1];
    #pragma unroll
    for (int qt = 0; qt < 2; ++qt) {
      float inv = 1.0f / lsum[qt];
      unsigned short* aop = AO + (bz * SS + q0 + qt * 16 + cl) * DM + h * KS + quad * 4;
      #pragma unroll
      for (int j = 0; j < 4; ++j) {
        unsigned short b0 = f2b(oa[qt][j][0] * inv), b1 = f2b(oa[qt][j][1] * inv);
        unsigned short b2 = f2b(oa[qt][j][2] * inv), b3 = f2b(oa[qt][j][3] * inv);
        uint2 pk;
        pk.x = (unsigned)b0 | ((unsigned)b1 << 16);
        pk.y = (unsigned)b2 | ((unsigned)b3 << 16);
        *(uint2*)(aop + j * 16) = pk;
      }
    }
  }
}

// ---- output GEMM: 256x128 tile, 8 waves, BK=32 dbuf + vmcnt(3) (R22) ----
__global__ __launch_bounds__(512) void gemm_out_kernel(
    const unsigned short* __restrict__ ao, const unsigned short* __restrict__ wot,
    const float* __restrict__ bo, float* __restrict__ out) {
  __shared__ __align__(16) unsigned short smem[24576]; // A [2][8192] | B @16384 [2][4096]
  // id&7 = n-panel (XCD class): B-panel 256KB L2-hot across its 16 m-tiles.
  int id = blockIdx.x;
  int m0 = (id >> 3) * 256, n0 = (id & 7) * 128;
  int t = threadIdx.x, w = t >> 6, lane = t & 63, cl = lane & 15, quad = lane >> 4;
  int wr = (w >> 1) * 64, wc = (w & 1) * 64;
  floatx4 acc[4][4];
  #pragma unroll
  for (int i = 0; i < 4; ++i)
    #pragma unroll
    for (int j = 0; j < 4; ++j)
      acc[i][j] = floatx4{0.f, 0.f, 0.f, 0.f};

  auto stage = [&](int kc, int buf) {
    #pragma unroll
    for (int i = 0; i < 2; ++i) {
      int c = i * 512 + t;
      int row = c >> 2, col = (c & 3) ^ (row & 3);
      async16(ao + (m0 + row) * HKD + kc * 32 + col * 8, &smem[buf * 8192 + c * 8]);
    }
    {
      int c = t;
      int row = c >> 2, col = (c & 3) ^ (row & 3);
      async16(wot + (n0 + row) * HKD + kc * 32 + col * 8, &smem[16384 + buf * 4096 + c * 8]);
    }
  };
  stage(0, 0);
  stage(1, 1);

  for (int kc = 0; kc < HKD / 32; ++kc) {
    int cur = kc & 1;
    if (kc < HKD / 32 - 1) asm volatile("s_waitcnt vmcnt(3)" ::: "memory");
    else                   asm volatile("s_waitcnt vmcnt(0)" ::: "memory");
    BAR();
    const unsigned short* Ac = &smem[cur * 8192];
    const unsigned short* Bc = &smem[16384 + cur * 4096];
    short8 a[4], b[4];
    #pragma unroll
    for (int i = 0; i < 4; ++i)
      a[i] = *(const short8*)&Ac[(wr + i * 16 + cl) * 32 + ((quad ^ (cl & 3)) * 8)];
    #pragma unroll
    for (int j = 0; j < 4; ++j)
      b[j] = *(const short8*)&Bc[(wc + j * 16 + cl) * 32 + ((quad ^ (cl & 3)) * 8)];
    #pragma unroll
    for (int i = 0; i < 4; ++i)
      #pragma unroll
      for (int j = 0; j < 4; ++j)
        acc[i][j] = mfma16(a[i], b[j], acc[i][j]);
    BAR();
    if (kc + 2 < HKD / 32) stage(kc + 2, cur);
  }
  #pragma unroll
  for (int j = 0; j < 4; ++j) {
    float bj = bo[n0 + wc + j * 16 + cl];
    #pragma unroll
    for (int i = 0; i < 4; ++i)
      #pragma unroll
      for (int r = 0; r < 4; ++r) {
        int token = m0 + wr + i * 16 + quad * 4 + r;
        out[token * DM + n0 + wc + j * 16 + cl] = acc[i][j][r] + bj;
      }
  }
}

extern "C" void kernel_launch(void* const* d_in, const int* in_sizes, int n_in,
                              void* d_out, int out_size, void* d_ws, size_t ws_size,
                              hipStream_t stream) {
  const float* x  = (const float*)d_in[0];
  const float* Wq = (const float*)d_in[1];
  const float* bq = (const float*)d_in[2];
  const float* Wk = (const float*)d_in[3];
  const float* bk = (const float*)d_in[4];
  const float* Wv = (const float*)d_in[5];
  const float* bv = (const float*)d_in[6];
  const float* Wo = (const float*)d_in[7];
  const float* bo = (const float*)d_in[8];
  float* out = (float*)d_out;
  char* ws = (char*)d_ws;
  unsigned short* xb  = (unsigned short*)(ws);                       // 8 MiB
  unsigned short* wqt = (unsigned short*)(ws + (8ull  << 20));       // 2 MiB
  unsigned short* wkt = (unsigned short*)(ws + (10ull << 20));       // 2 MiB
  unsigned short* wvt = (unsigned short*)(ws + (12ull << 20));       // 2 MiB
  unsigned short* wot = (unsigned short*)(ws + (14ull << 20));       // 2 MiB
  unsigned short* qb  = (unsigned short*)(ws + (16ull << 20));       // 8 MiB
  unsigned short* kbf = (unsigned short*)(ws + (24ull << 20));       // 8 MiB
  unsigned short* vt  = (unsigned short*)(ws + (40ull << 20));       // 8 MiB
  unsigned short* ao  = (unsigned short*)(ws + (48ull << 20));       // 8 MiB

  hipLaunchKernelGGL(prep_kernel, dim3(NT * DM / 1024 + 1024), dim3(256), 0, stream,
                     x, Wq, Wk, Wv, Wo, xb, wqt, wkt, wvt, wot);
  hipLaunchKernelGGL(gemm_qkv_kernel, dim3(384), dim3(512), 0, stream,
                     xb, wqt, wkt, wvt, bq, bk, bv, qb, kbf, vt);
  hipLaunchKernelGGL(attn_kernel, dim3(SS / 128, NH, BB), dim3(512), 0, stream, qb, kbf, vt, ao);
  hipLaunchKernelGGL(gemm_out_kernel, dim3(128), dim3(512), 0, stream, ao, wot, bo, out);
}

// Round 15
// 191.438 us; speedup vs baseline: 1.0008x; 1.0008x over previous
//
#include <hip/hip_runtime.h>

// MHA forward, B=2, S=2048, D=1024, H=16, K=64, fp32 in/out, bf16 MFMA internally.
// R27 = exact R22/R25 (best measured: 189.7us) — FINAL locked configuration.
// R26's 2-WG/CU occupancy test came back negative (attn 47.2 -> 51.1us despite
// occupancy 18->33%: halved LDS reuse outweighs phase diversity). Complete attn
// ablation ledger (R14-R26): barrier-halving null, LDS-volume +4%, conflict-fix
// -13%, cross-iter-pipe null, 2-tile-pass -13%, fusion -54%, depth-3 -10%,
// 2WG/CU -8%, XCD-swizzle +2% (FETCH 69.7->12.35MB). Config: prep | gemm_qkv
// 256x128 x 8w z-colocated | attn R17 8w x 64 q-rows split-K-2, tri-buf depth-2,
// XCD head-colocation | gemm_out 256x128 x 8w B-panel-per-XCD.

#define NH 16
#define KS 64
#define DM 1024
#define BB 2
#define SS 2048
#define NT (BB*SS)   // 4096 tokens
#define HKD 1024     // NH*KS
#define L2E 1.44269504088896340736f

typedef __attribute__((ext_vector_type(4))) float floatx4;
typedef __attribute__((ext_vector_type(8))) short short8;

#define BAR() asm volatile("s_barrier" ::: "memory")

__device__ __forceinline__ unsigned short f2b(float f) {
  unsigned u = __builtin_bit_cast(unsigned, f);
  u = (u + 0x7fffu + ((u >> 16) & 1u)) >> 16;
  return (unsigned short)u;
}

__device__ __forceinline__ floatx4 mfma16(short8 a, short8 b, floatx4 c) {
  return __builtin_amdgcn_mfma_f32_16x16x32_bf16(a, b, c, 0, 0, 0);
}

// async global->LDS, 16B per lane. LDS dest must be wave-uniform base + lane*16.
__device__ __forceinline__ void async16(const void* g, void* l) {
  __builtin_amdgcn_global_load_lds(
      (const __attribute__((address_space(1))) unsigned int*)g,
      (__attribute__((address_space(3))) unsigned int*)l, 16, 0, 0);
}

// ------ prep: cast x (f32->bf16) + transpose+cast all W, one launch ------
__global__ __launch_bounds__(256) void prep_kernel(
    const float* __restrict__ x,
    const float* __restrict__ Wq, const float* __restrict__ Wk,
    const float* __restrict__ Wv, const float* __restrict__ Wo,
    unsigned short* __restrict__ xb,
    unsigned short* __restrict__ wqt, unsigned short* __restrict__ wkt,
    unsigned short* __restrict__ wvt, unsigned short* __restrict__ wot) {
  int bid = blockIdx.x;
  if (bid < NT * DM / 1024) {
    int i = (bid * 256 + threadIdx.x) * 4;
    float4 v = *(const float4*)(x + i);
    ushort4 o;
    o.x = f2b(v.x); o.y = f2b(v.y); o.z = f2b(v.z); o.w = f2b(v.w);
    *(ushort4*)(xb + i) = o;
    return;
  }
  int b2 = bid - NT * DM / 1024;
  int z = b2 >> 8;
  const float* W; unsigned short* Wt;
  if (z == 0)      { W = Wq; Wt = wqt; }
  else if (z == 1) { W = Wk; Wt = wkt; }
  else if (z == 2) { W = Wv; Wt = wvt; }
  else             { W = Wo; Wt = wot; }
  __shared__ __align__(16) unsigned short tile[64][80];
  int k0 = (b2 & 15) * 64, n0 = ((b2 >> 4) & 15) * 64;
  int t = threadIdx.x;
  int c0 = (t & 15) * 4, r = t >> 4;
  #pragma unroll
  for (int p = 0; p < 4; ++p) {
    int rr = r + p * 16;
    float4 v = *(const float4*)(W + (k0 + rr) * DM + n0 + c0);
    tile[c0 + 0][rr] = f2b(v.x);
    tile[c0 + 1][rr] = f2b(v.y);
    tile[c0 + 2][rr] = f2b(v.z);
    tile[c0 + 3][rr] = f2b(v.w);
  }
  __syncthreads();
  int cc0 = (t & 7) * 8, rn = t >> 3;
  #pragma unroll
  for (int p = 0; p < 2; ++p) {
    int nn = rn + p * 32;
    *(short8*)(Wt + (n0 + nn) * DM + k0 + cc0) = *(const short8*)(&tile[nn][cc0]);
  }
}

// ---- QKV GEMM: 256x128 tile, 8 waves, BK=32 dbuf + vmcnt(3) prefetch (R21) ----
__global__ __launch_bounds__(512) void gemm_qkv_kernel(
    const unsigned short* __restrict__ xb,
    const unsigned short* __restrict__ wqt, const unsigned short* __restrict__ wkt,
    const unsigned short* __restrict__ wvt,
    const float* __restrict__ bq, const float* __restrict__ bk, const float* __restrict__ bv,
    unsigned short* __restrict__ qb, unsigned short* __restrict__ kbuf,
    unsigned short* __restrict__ vt) {
  __shared__ __align__(16) unsigned short smem[24576]; // A [2][8192] | B @16384 [2][4096]
  // id = y + 8*(z + 3*x): y = XCD/B-panel class, z fastest within x -> A L2-hot x3
  int id = blockIdx.x;
  int y = id & 7, r2 = id >> 3;
  int zid = r2 % 3, xm = r2 / 3;
  const unsigned short* Bt; const float* bias; float scale;
  if (zid == 0)      { Bt = wqt; bias = bq; scale = 0.125f * L2E; }
  else if (zid == 1) { Bt = wkt; bias = bk; scale = 1.0f; }
  else               { Bt = wvt; bias = bv; scale = 1.0f; }
  int m0 = xm * 256, n0 = y * 128;
  int t = threadIdx.x, w = t >> 6, lane = t & 63, cl = lane & 15, quad = lane >> 4;
  int wr = (w >> 1) * 64, wc = (w & 1) * 64;
  floatx4 acc[4][4];
  #pragma unroll
  for (int i = 0; i < 4; ++i)
    #pragma unroll
    for (int j = 0; j < 4; ++j)
      acc[i][j] = floatx4{0.f, 0.f, 0.f, 0.f};

  auto stage = [&](int kc, int buf) {
    #pragma unroll
    for (int i = 0; i < 2; ++i) {
      int c = i * 512 + t;
      int row = c >> 2, col = (c & 3) ^ (row & 3);
      async16(xb + (m0 + row) * DM + kc * 32 + col * 8, &smem[buf * 8192 + c * 8]);
    }
    {
      int c = t;
      int row = c >> 2, col = (c & 3) ^ (row & 3);
      async16(Bt + (n0 + row) * DM + kc * 32 + col * 8, &smem[16384 + buf * 4096 + c * 8]);
    }
  };
  stage(0, 0);
  stage(1, 1);

  for (int kc = 0; kc < DM / 32; ++kc) {
    int cur = kc & 1;
    if (kc < DM / 32 - 1) asm volatile("s_waitcnt vmcnt(3)" ::: "memory");
    else                  asm volatile("s_waitcnt vmcnt(0)" ::: "memory");
    BAR();
    const unsigned short* Ac = &smem[cur * 8192];
    const unsigned short* Bc = &smem[16384 + cur * 4096];
    short8 a[4], b[4];
    #pragma unroll
    for (int i = 0; i < 4; ++i)
      a[i] = *(const short8*)&Ac[(wr + i * 16 + cl) * 32 + ((quad ^ (cl & 3)) * 8)];
    #pragma unroll
    for (int j = 0; j < 4; ++j)
      b[j] = *(const short8*)&Bc[(wc + j * 16 + cl) * 32 + ((quad ^ (cl & 3)) * 8)];
    #pragma unroll
    for (int i = 0; i < 4; ++i)
      #pragma unroll
      for (int j = 0; j < 4; ++j)
        acc[i][j] = mfma16(a[i], b[j], acc[i][j]);
    BAR();
    if (kc + 2 < DM / 32) stage(kc + 2, cur);
  }
  __syncthreads();

  int h = (n0 + wc) >> 6;
  if (zid < 2) {
    unsigned short* dst = (zid == 0) ? qb : kbuf;
    #pragma unroll
    for (int j = 0; j < 4; ++j) {
      float bj = bias[n0 + wc + j * 16 + cl];
      int kd = j * 16 + cl;
      #pragma unroll
      for (int i = 0; i < 4; ++i)
        #pragma unroll
        for (int r = 0; r < 4; ++r) {
          int token = m0 + wr + i * 16 + quad * 4 + r;
          int bz = token >> 11, s = token & (SS - 1);
          float val = (acc[i][j][r] + bj) * scale;
          dst[(((bz * NH + h) * SS + s) << 6) + kd] = f2b(val);
        }
    }
  } else {
    // V: transpose via per-wave LDS region, two rounds of 32 kd (8x2304 <= 24576)
    unsigned short* tr = &smem[w * 2304];
    int tokbase = m0 + wr;
    int bz = tokbase >> 11, s0 = tokbase & (SS - 1);
    unsigned short* vdst = vt + (((bz * NH + h) * KS) * SS) + s0;
    #pragma unroll
    for (int jr = 0; jr < 2; ++jr) {
      #pragma unroll
      for (int jj = 0; jj < 2; ++jj) {
        int j = jr * 2 + jj;
        float bj = bias[n0 + wc + j * 16 + cl];
        #pragma unroll
        for (int i = 0; i < 4; ++i) {
          unsigned short b0 = f2b(acc[i][j][0] + bj), b1 = f2b(acc[i][j][1] + bj);
          unsigned short b2 = f2b(acc[i][j][2] + bj), b3 = f2b(acc[i][j][3] + bj);
          uint2 pk;
          pk.x = (unsigned)b0 | ((unsigned)b1 << 16);
          pk.y = (unsigned)b2 | ((unsigned)b3 << 16);
          *(uint2*)&tr[(jj * 16 + cl) * 72 + i * 16 + quad * 4] = pk;
        }
      }
      asm volatile("s_waitcnt lgkmcnt(0)" ::: "memory");
      #pragma unroll
      for (int p = 0; p < 4; ++p) {
        int row = p * 8 + (lane >> 3);
        int tk = (lane & 7) * 8;
        short8 vv = *(const short8*)&tr[row * 72 + tk];
        *(short8*)(vdst + (jr * 32 + row) * SS + tk) = vv;
      }
    }
  }
}

// ---- attention: R17 verbatim — split-K-2 dual-stream, 8 waves x 64 q-rows ----
__global__ __launch_bounds__(512) void attn_kernel(
    const unsigned short* __restrict__ Q, const unsigned short* __restrict__ Kb,
    const unsigned short* __restrict__ Vt, unsigned short* __restrict__ AO) {
  __shared__ __align__(16) unsigned short smem[40960];
  int t = threadIdx.x, w = t >> 6, lane = t & 63, cl = lane & 15, quad = lane >> 4;
  int clm = cl & 7, cl3 = cl & 3, cl2 = cl >> 2;
  int id = blockIdx.x + (SS / 256) * (blockIdx.y + NH * blockIdx.z);
  int c = id & 7, k = id >> 3;
  int head_lin = c + 8 * (k & 3);
  int qx = k >> 2;
  int h = head_lin & (NH - 1), bz = head_lin >> 4;
  int bh = bz * NH + h;
  int slice = w & 3, part = w >> 2;
  int q0 = qx * 256 + slice * 64;
  const unsigned short* Qp = Q + (bh * SS + q0) * KS;
  const unsigned short* Kp = Kb + bh * SS * KS;
  const unsigned short* Vp = Vt + bh * KS * SS;
  unsigned short* p_w = smem + 24576 + w * 2048;

  short8 qa[4][2];
  #pragma unroll
  for (int qt = 0; qt < 4; ++qt)
    #pragma unroll
    for (int cc = 0; cc < 2; ++cc)
      qa[qt][cc] = *(const short8*)(Qp + (qt * 16 + cl) * KS + cc * 32 + quad * 8);

  short8 ones;
  #pragma unroll
  for (int j = 0; j < 8; ++j) ones[j] = (short)0x3f80; // bf16 1.0

  floatx4 lacc[4];
  floatx4 oa[4][4];
  #pragma unroll
  for (int qt = 0; qt < 4; ++qt) {
    lacc[qt] = floatx4{0.f, 0.f, 0.f, 0.f};
    #pragma unroll
    for (int j = 0; j < 4; ++j) oa[qt][j] = floatx4{0.f, 0.f, 0.f, 0.f};
  }

  int st = t >> 8, lt = t & 255;
  int krow = lt >> 3, kcol = (lt & 7) ^ (krow & 7);
  int vd = lt >> 2, vcol = ((lt & 3) ^ (vd & 3) ^ ((vd >> 2) & 3)) & 3;
  auto stage = [&](int it, int buf) {
    async16(Kp + (st * 1024 + it * 32 + krow) * KS + kcol * 8,
            &smem[(st * 3 + buf) * 2048 + lt * 8]);
    async16(Vp + vd * SS + st * 1024 + it * 32 + vcol * 8,
            &smem[12288 + (st * 3 + buf) * 2048 + lt * 8]);
  };
  stage(0, 0);
  stage(1, 1);

  const int NIT = 1024 / 32;
  int cur = 0;
  for (int it = 0; it < NIT; ++it) {
    if (it < NIT - 1) asm volatile("s_waitcnt vmcnt(2)" ::: "memory");
    else              asm volatile("s_waitcnt vmcnt(0)" ::: "memory");
    BAR();
    if (it + 2 < NIT) {
      int sb = (cur >= 1) ? cur - 1 : 2; // (cur+2)%3
      stage(it + 2, sb);
    }
    const unsigned short* Kc = &smem[(part * 3 + cur) * 2048];
    const unsigned short* Vc = &smem[12288 + (part * 3 + cur) * 2048];

    floatx4 s[4][2];
    __builtin_amdgcn_s_setprio(1);
    #pragma unroll
    for (int kt = 0; kt < 2; ++kt) {
      short8 kb0 = *(const short8*)&Kc[(kt * 16 + cl) * 64 + ((quad ^ clm) * 8)];
      short8 kb1 = *(const short8*)&Kc[(kt * 16 + cl) * 64 + (((4 + quad) ^ clm) * 8)];
      #pragma unroll
      for (int qt = 0; qt < 4; ++qt) {
        floatx4 z = {0.f, 0.f, 0.f, 0.f};
        s[qt][kt] = mfma16(kb1, qa[qt][1], mfma16(kb0, qa[qt][0], z));
      }
    }
    __builtin_amdgcn_s_setprio(0);
    #pragma unroll
    for (int qt = 0; qt < 4; ++qt)
      #pragma unroll
      for (int kt = 0; kt < 2; ++kt) {
        unsigned u[4];
        #pragma unroll
        for (int r = 0; r < 4; ++r)
          u[r] = __builtin_bit_cast(unsigned, __builtin_amdgcn_exp2f(s[qt][kt][r]));
        uint2 pk;
        pk.x = __builtin_amdgcn_perm(u[1], u[0], 0x07060302);
        pk.y = __builtin_amdgcn_perm(u[3], u[2], 0x07060302);
        int blk = ((kt * 2 + (quad >> 1)) ^ cl3 ^ cl2) & 3;
        int off = qt * 512 + cl * 32 + blk * 8 + (quad & 1) * 4;
        *(uint2*)(p_w + off) = pk;
      }
    asm volatile("s_waitcnt lgkmcnt(0)" ::: "memory");
    short8 pa[4];
    __builtin_amdgcn_s_setprio(1);
    #pragma unroll
    for (int qt = 0; qt < 4; ++qt) {
      pa[qt] = *(const short8*)(p_w + qt * 512 + cl * 32 + (((quad ^ cl3 ^ cl2) & 3) * 8));
      lacc[qt] = mfma16(ones, pa[qt], lacc[qt]);
    }
    #pragma unroll
    for (int j = 0; j < 4; ++j) {
      short8 vb = *(const short8*)&Vc[(j * 16 + cl) * 32 + (((quad ^ cl3 ^ cl2) & 3) * 8)];
      #pragma unroll
      for (int qt = 0; qt < 4; ++qt)
        oa[qt][j] = mfma16(vb, pa[qt], oa[qt][j]);
    }
    __builtin_amdgcn_s_setprio(0);
    cur = (cur == 2) ? 0 : cur + 1;
  }

  __syncthreads();
  float* red = (float*)smem;
  float* base = red + slice * 4352;
  if (part == 1) {
    #pragma unroll
    for (int qt = 0; qt < 4; ++qt)
      #pragma unroll
      for (int j = 0; j < 4; ++j)
        *(floatx4*)(base + (((qt * 4 + j) * 64 + lane) << 2)) = oa[qt][j];
    #pragma unroll
    for (int qt = 0; qt < 4; ++qt)
      base[4096 + lane * 4 + qt] = lacc[qt][0];
  }
  __syncthreads();
  if (part == 0) {
    #pragma unroll
    for (int qt = 0; qt < 4; ++qt)
      #pragma unroll
      for (int j = 0; j < 4; ++j)
        oa[qt][j] += *(const floatx4*)(base + (((qt * 4 + j) * 64 + lane) << 2));
    float lsum[4];
    #pragma unroll
    for (int qt = 0; qt < 4; ++qt)
      lsum[qt] = lacc[qt][0] + base[4096 + lane * 4 + qt];
    #pragma unroll
    for (int qt = 0; qt < 4; ++qt) {
      float inv = 1.0f / lsum[qt];
      unsigned short* aop = AO + (bz * SS + q0 + qt * 16 + cl) * DM + h * KS + quad * 4;
      #pragma unroll
      for (int j = 0; j < 4; ++j) {
        unsigned short b0 = f2b(oa[qt][j][0] * inv), b1 = f2b(oa[qt][j][1] * inv);
        unsigned short b2 = f2b(oa[qt][j][2] * inv), b3 = f2b(oa[qt][j][3] * inv);
        uint2 pk;
        pk.x = (unsigned)b0 | ((unsigned)b1 << 16);
        pk.y = (unsigned)b2 | ((unsigned)b3 << 16);
        *(uint2*)(aop + j * 16) = pk;
      }
    }
  }
}

// ---- output GEMM: 256x128 tile, 8 waves, BK=32 dbuf + vmcnt(3) (R22) ----
__global__ __launch_bounds__(512) void gemm_out_kernel(
    const unsigned short* __restrict__ ao, const unsigned short* __restrict__ wot,
    const float* __restrict__ bo, float* __restrict__ out) {
  __shared__ __align__(16) unsigned short smem[24576]; // A [2][8192] | B @16384 [2][4096]
  // id&7 = n-panel (XCD class): B-panel 256KB L2-hot across its 16 m-tiles.
  int id = blockIdx.x;
  int m0 = (id >> 3) * 256, n0 = (id & 7) * 128;
  int t = threadIdx.x, w = t >> 6, lane = t & 63, cl = lane & 15, quad = lane >> 4;
  int wr = (w >> 1) * 64, wc = (w & 1) * 64;
  floatx4 acc[4][4];
  #pragma unroll
  for (int i = 0; i < 4; ++i)
    #pragma unroll
    for (int j = 0; j < 4; ++j)
      acc[i][j] = floatx4{0.f, 0.f, 0.f, 0.f};

  auto stage = [&](int kc, int buf) {
    #pragma unroll
    for (int i = 0; i < 2; ++i) {
      int c = i * 512 + t;
      int row = c >> 2, col = (c & 3) ^ (row & 3);
      async16(ao + (m0 + row) * HKD + kc * 32 + col * 8, &smem[buf * 8192 + c * 8]);
    }
    {
      int c = t;
      int row = c >> 2, col = (c & 3) ^ (row & 3);
      async16(wot + (n0 + row) * HKD + kc * 32 + col * 8, &smem[16384 + buf * 4096 + c * 8]);
    }
  };
  stage(0, 0);
  stage(1, 1);

  for (int kc = 0; kc < HKD / 32; ++kc) {
    int cur = kc & 1;
    if (kc < HKD / 32 - 1) asm volatile("s_waitcnt vmcnt(3)" ::: "memory");
    else                   asm volatile("s_waitcnt vmcnt(0)" ::: "memory");
    BAR();
    const unsigned short* Ac = &smem[cur * 8192];
    const unsigned short* Bc = &smem[16384 + cur * 4096];
    short8 a[4], b[4];
    #pragma unroll
    for (int i = 0; i < 4; ++i)
      a[i] = *(const short8*)&Ac[(wr + i * 16 + cl) * 32 + ((quad ^ (cl & 3)) * 8)];
    #pragma unroll
    for (int j = 0; j < 4; ++j)
      b[j] = *(const short8*)&Bc[(wc + j * 16 + cl) * 32 + ((quad ^ (cl & 3)) * 8)];
    #pragma unroll
    for (int i = 0; i < 4; ++i)
      #pragma unroll
      for (int j = 0; j < 4; ++j)
        acc[i][j] = mfma16(a[i], b[j], acc[i][j]);
    BAR();
    if (kc + 2 < HKD / 32) stage(kc + 2, cur);
  }
  #pragma unroll
  for (int j = 0; j < 4; ++j) {
    float bj = bo[n0 + wc + j * 16 + cl];
    #pragma unroll
    for (int i = 0; i < 4; ++i)
      #pragma unroll
      for (int r = 0; r < 4; ++r) {
        int token = m0 + wr + i * 16 + quad * 4 + r;
        out[token * DM + n0 + wc + j * 16 + cl] = acc[i][j][r] + bj;
      }
  }
}

extern "C" void kernel_launch(void* const* d_in, const int* in_sizes, int n_in,
                              void* d_out, int out_size, void* d_ws, size_t ws_size,
                              hipStream_t stream) {
  const float* x  = (const float*)d_in[0];
  const float* Wq = (const float*)d_in[1];
  const float* bq = (const float*)d_in[2];
  const float* Wk = (const float*)d_in[3];
  const float* bk = (const float*)d_in[4];
  const float* Wv = (const float*)d_in[5];
  const float* bv = (const float*)d_in[6];
  const float* Wo = (const float*)d_in[7];
  const float* bo = (const float*)d_in[8];
  float* out = (float*)d_out;
  char* ws = (char*)d_ws;
  unsigned short* xb  = (unsigned short*)(ws);                       // 8 MiB
  unsigned short* wqt = (unsigned short*)(ws + (8ull  << 20));       // 2 MiB
  unsigned short* wkt = (unsigned short*)(ws + (10ull << 20));       // 2 MiB
  unsigned short* wvt = (unsigned short*)(ws + (12ull << 20));       // 2 MiB
  unsigned short* wot = (unsigned short*)(ws + (14ull << 20));       // 2 MiB
  unsigned short* qb  = (unsigned short*)(ws + (16ull << 20));       // 8 MiB
  unsigned short* kbf = (unsigned short*)(ws + (24ull << 20));       // 8 MiB
  unsigned short* vt  = (unsigned short*)(ws + (40ull << 20));       // 8 MiB
  unsigned short* ao  = (unsigned short*)(ws + (48ull << 20));       // 8 MiB

  hipLaunchKernelGGL(prep_kernel, dim3(NT * DM / 1024 + 1024), dim3(256), 0, stream,
                     x, Wq, Wk, Wv, Wo, xb, wqt, wkt, wvt, wot);
  hipLaunchKernelGGL(gemm_qkv_kernel, dim3(384), dim3(512), 0, stream,
                     xb, wqt, wkt, wvt, bq, bk, bv, qb, kbf, vt);
  hipLaunchKernelGGL(attn_kernel, dim3(SS / 256, NH, BB), dim3(512), 0, stream, qb, kbf, vt, ao);
  hipLaunchKernelGGL(gemm_out_kernel, dim3(128), dim3(512), 0, stream, ao, wot, bo, out);
}

// Round 16
// 184.635 us; speedup vs baseline: 1.0377x; 1.0368x over previous
//
#include <hip/hip_runtime.h>

// MHA forward, B=2, S=2048, D=1024, H=16, K=64, fp32 in/out, bf16 MFMA internally.
// R28 = R27 (locked best, 189.7-191.4us band) + gemm_out re-tiled 128x128 x
// 8 waves, grid 256. Rationale: R22's gemm_out ran only 128 WGs on 256 CUs —
// half the chip idle (573 TF on the active half = 46% of their dense peak).
// 128x128 tile doubles grid to full chip, keeps B-panel-per-XCD (id&7), 32KB
// LDS -> 4 WG/CU co-residency. Code lifted from R20 phase-4 (correctness-
// verified there). prep / gemm_qkv (256x128 z-colocated) / attn (R17) unchanged.

#define NH 16
#define KS 64
#define DM 1024
#define BB 2
#define SS 2048
#define NT (BB*SS)   // 4096 tokens
#define HKD 1024     // NH*KS
#define L2E 1.44269504088896340736f

typedef __attribute__((ext_vector_type(4))) float floatx4;
typedef __attribute__((ext_vector_type(8))) short short8;

#define BAR() asm volatile("s_barrier" ::: "memory")

__device__ __forceinline__ unsigned short f2b(float f) {
  unsigned u = __builtin_bit_cast(unsigned, f);
  u = (u + 0x7fffu + ((u >> 16) & 1u)) >> 16;
  return (unsigned short)u;
}

__device__ __forceinline__ floatx4 mfma16(short8 a, short8 b, floatx4 c) {
  return __builtin_amdgcn_mfma_f32_16x16x32_bf16(a, b, c, 0, 0, 0);
}

// async global->LDS, 16B per lane. LDS dest must be wave-uniform base + lane*16.
__device__ __forceinline__ void async16(const void* g, void* l) {
  __builtin_amdgcn_global_load_lds(
      (const __attribute__((address_space(1))) unsigned int*)g,
      (__attribute__((address_space(3))) unsigned int*)l, 16, 0, 0);
}

// ------ prep: cast x (f32->bf16) + transpose+cast all W, one launch ------
__global__ __launch_bounds__(256) void prep_kernel(
    const float* __restrict__ x,
    const float* __restrict__ Wq, const float* __restrict__ Wk,
    const float* __restrict__ Wv, const float* __restrict__ Wo,
    unsigned short* __restrict__ xb,
    unsigned short* __restrict__ wqt, unsigned short* __restrict__ wkt,
    unsigned short* __restrict__ wvt, unsigned short* __restrict__ wot) {
  int bid = blockIdx.x;
  if (bid < NT * DM / 1024) {
    int i = (bid * 256 + threadIdx.x) * 4;
    float4 v = *(const float4*)(x + i);
    ushort4 o;
    o.x = f2b(v.x); o.y = f2b(v.y); o.z = f2b(v.z); o.w = f2b(v.w);
    *(ushort4*)(xb + i) = o;
    return;
  }
  int b2 = bid - NT * DM / 1024;
  int z = b2 >> 8;
  const float* W; unsigned short* Wt;
  if (z == 0)      { W = Wq; Wt = wqt; }
  else if (z == 1) { W = Wk; Wt = wkt; }
  else if (z == 2) { W = Wv; Wt = wvt; }
  else             { W = Wo; Wt = wot; }
  __shared__ __align__(16) unsigned short tile[64][80];
  int k0 = (b2 & 15) * 64, n0 = ((b2 >> 4) & 15) * 64;
  int t = threadIdx.x;
  int c0 = (t & 15) * 4, r = t >> 4;
  #pragma unroll
  for (int p = 0; p < 4; ++p) {
    int rr = r + p * 16;
    float4 v = *(const float4*)(W + (k0 + rr) * DM + n0 + c0);
    tile[c0 + 0][rr] = f2b(v.x);
    tile[c0 + 1][rr] = f2b(v.y);
    tile[c0 + 2][rr] = f2b(v.z);
    tile[c0 + 3][rr] = f2b(v.w);
  }
  __syncthreads();
  int cc0 = (t & 7) * 8, rn = t >> 3;
  #pragma unroll
  for (int p = 0; p < 2; ++p) {
    int nn = rn + p * 32;
    *(short8*)(Wt + (n0 + nn) * DM + k0 + cc0) = *(const short8*)(&tile[nn][cc0]);
  }
}

// ---- QKV GEMM: 256x128 tile, 8 waves, BK=32 dbuf + vmcnt(3) prefetch (R21) ----
__global__ __launch_bounds__(512) void gemm_qkv_kernel(
    const unsigned short* __restrict__ xb,
    const unsigned short* __restrict__ wqt, const unsigned short* __restrict__ wkt,
    const unsigned short* __restrict__ wvt,
    const float* __restrict__ bq, const float* __restrict__ bk, const float* __restrict__ bv,
    unsigned short* __restrict__ qb, unsigned short* __restrict__ kbuf,
    unsigned short* __restrict__ vt) {
  __shared__ __align__(16) unsigned short smem[24576]; // A [2][8192] | B @16384 [2][4096]
  // id = y + 8*(z + 3*x): y = XCD/B-panel class, z fastest within x -> A L2-hot x3
  int id = blockIdx.x;
  int y = id & 7, r2 = id >> 3;
  int zid = r2 % 3, xm = r2 / 3;
  const unsigned short* Bt; const float* bias; float scale;
  if (zid == 0)      { Bt = wqt; bias = bq; scale = 0.125f * L2E; }
  else if (zid == 1) { Bt = wkt; bias = bk; scale = 1.0f; }
  else               { Bt = wvt; bias = bv; scale = 1.0f; }
  int m0 = xm * 256, n0 = y * 128;
  int t = threadIdx.x, w = t >> 6, lane = t & 63, cl = lane & 15, quad = lane >> 4;
  int wr = (w >> 1) * 64, wc = (w & 1) * 64;
  floatx4 acc[4][4];
  #pragma unroll
  for (int i = 0; i < 4; ++i)
    #pragma unroll
    for (int j = 0; j < 4; ++j)
      acc[i][j] = floatx4{0.f, 0.f, 0.f, 0.f};

  auto stage = [&](int kc, int buf) {
    #pragma unroll
    for (int i = 0; i < 2; ++i) {
      int c = i * 512 + t;
      int row = c >> 2, col = (c & 3) ^ (row & 3);
      async16(xb + (m0 + row) * DM + kc * 32 + col * 8, &smem[buf * 8192 + c * 8]);
    }
    {
      int c = t;
      int row = c >> 2, col = (c & 3) ^ (row & 3);
      async16(Bt + (n0 + row) * DM + kc * 32 + col * 8, &smem[16384 + buf * 4096 + c * 8]);
    }
  };
  stage(0, 0);
  stage(1, 1);

  for (int kc = 0; kc < DM / 32; ++kc) {
    int cur = kc & 1;
    if (kc < DM / 32 - 1) asm volatile("s_waitcnt vmcnt(3)" ::: "memory");
    else                  asm volatile("s_waitcnt vmcnt(0)" ::: "memory");
    BAR();
    const unsigned short* Ac = &smem[cur * 8192];
    const unsigned short* Bc = &smem[16384 + cur * 4096];
    short8 a[4], b[4];
    #pragma unroll
    for (int i = 0; i < 4; ++i)
      a[i] = *(const short8*)&Ac[(wr + i * 16 + cl) * 32 + ((quad ^ (cl & 3)) * 8)];
    #pragma unroll
    for (int j = 0; j < 4; ++j)
      b[j] = *(const short8*)&Bc[(wc + j * 16 + cl) * 32 + ((quad ^ (cl & 3)) * 8)];
    #pragma unroll
    for (int i = 0; i < 4; ++i)
      #pragma unroll
      for (int j = 0; j < 4; ++j)
        acc[i][j] = mfma16(a[i], b[j], acc[i][j]);
    BAR();
    if (kc + 2 < DM / 32) stage(kc + 2, cur);
  }
  __syncthreads();

  int h = (n0 + wc) >> 6;
  if (zid < 2) {
    unsigned short* dst = (zid == 0) ? qb : kbuf;
    #pragma unroll
    for (int j = 0; j < 4; ++j) {
      float bj = bias[n0 + wc + j * 16 + cl];
      int kd = j * 16 + cl;
      #pragma unroll
      for (int i = 0; i < 4; ++i)
        #pragma unroll
        for (int r = 0; r < 4; ++r) {
          int token = m0 + wr + i * 16 + quad * 4 + r;
          int bz = token >> 11, s = token & (SS - 1);
          float val = (acc[i][j][r] + bj) * scale;
          dst[(((bz * NH + h) * SS + s) << 6) + kd] = f2b(val);
        }
    }
  } else {
    // V: transpose via per-wave LDS region, two rounds of 32 kd (8x2304 <= 24576)
    unsigned short* tr = &smem[w * 2304];
    int tokbase = m0 + wr;
    int bz = tokbase >> 11, s0 = tokbase & (SS - 1);
    unsigned short* vdst = vt + (((bz * NH + h) * KS) * SS) + s0;
    #pragma unroll
    for (int jr = 0; jr < 2; ++jr) {
      #pragma unroll
      for (int jj = 0; jj < 2; ++jj) {
        int j = jr * 2 + jj;
        float bj = bias[n0 + wc + j * 16 + cl];
        #pragma unroll
        for (int i = 0; i < 4; ++i) {
          unsigned short b0 = f2b(acc[i][j][0] + bj), b1 = f2b(acc[i][j][1] + bj);
          unsigned short b2 = f2b(acc[i][j][2] + bj), b3 = f2b(acc[i][j][3] + bj);
          uint2 pk;
          pk.x = (unsigned)b0 | ((unsigned)b1 << 16);
          pk.y = (unsigned)b2 | ((unsigned)b3 << 16);
          *(uint2*)&tr[(jj * 16 + cl) * 72 + i * 16 + quad * 4] = pk;
        }
      }
      asm volatile("s_waitcnt lgkmcnt(0)" ::: "memory");
      #pragma unroll
      for (int p = 0; p < 4; ++p) {
        int row = p * 8 + (lane >> 3);
        int tk = (lane & 7) * 8;
        short8 vv = *(const short8*)&tr[row * 72 + tk];
        *(short8*)(vdst + (jr * 32 + row) * SS + tk) = vv;
      }
    }
  }
}

// ---- attention: R17 verbatim — split-K-2 dual-stream, 8 waves x 64 q-rows ----
__global__ __launch_bounds__(512) void attn_kernel(
    const unsigned short* __restrict__ Q, const unsigned short* __restrict__ Kb,
    const unsigned short* __restrict__ Vt, unsigned short* __restrict__ AO) {
  __shared__ __align__(16) unsigned short smem[40960];
  int t = threadIdx.x, w = t >> 6, lane = t & 63, cl = lane & 15, quad = lane >> 4;
  int clm = cl & 7, cl3 = cl & 3, cl2 = cl >> 2;
  int id = blockIdx.x + (SS / 256) * (blockIdx.y + NH * blockIdx.z);
  int c = id & 7, k = id >> 3;
  int head_lin = c + 8 * (k & 3);
  int qx = k >> 2;
  int h = head_lin & (NH - 1), bz = head_lin >> 4;
  int bh = bz * NH + h;
  int slice = w & 3, part = w >> 2;
  int q0 = qx * 256 + slice * 64;
  const unsigned short* Qp = Q + (bh * SS + q0) * KS;
  const unsigned short* Kp = Kb + bh * SS * KS;
  const unsigned short* Vp = Vt + bh * KS * SS;
  unsigned short* p_w = smem + 24576 + w * 2048;

  short8 qa[4][2];
  #pragma unroll
  for (int qt = 0; qt < 4; ++qt)
    #pragma unroll
    for (int cc = 0; cc < 2; ++cc)
      qa[qt][cc] = *(const short8*)(Qp + (qt * 16 + cl) * KS + cc * 32 + quad * 8);

  short8 ones;
  #pragma unroll
  for (int j = 0; j < 8; ++j) ones[j] = (short)0x3f80; // bf16 1.0

  floatx4 lacc[4];
  floatx4 oa[4][4];
  #pragma unroll
  for (int qt = 0; qt < 4; ++qt) {
    lacc[qt] = floatx4{0.f, 0.f, 0.f, 0.f};
    #pragma unroll
    for (int j = 0; j < 4; ++j) oa[qt][j] = floatx4{0.f, 0.f, 0.f, 0.f};
  }

  int st = t >> 8, lt = t & 255;
  int krow = lt >> 3, kcol = (lt & 7) ^ (krow & 7);
  int vd = lt >> 2, vcol = ((lt & 3) ^ (vd & 3) ^ ((vd >> 2) & 3)) & 3;
  auto stage = [&](int it, int buf) {
    async16(Kp + (st * 1024 + it * 32 + krow) * KS + kcol * 8,
            &smem[(st * 3 + buf) * 2048 + lt * 8]);
    async16(Vp + vd * SS + st * 1024 + it * 32 + vcol * 8,
            &smem[12288 + (st * 3 + buf) * 2048 + lt * 8]);
  };
  stage(0, 0);
  stage(1, 1);

  const int NIT = 1024 / 32;
  int cur = 0;
  for (int it = 0; it < NIT; ++it) {
    if (it < NIT - 1) asm volatile("s_waitcnt vmcnt(2)" ::: "memory");
    else              asm volatile("s_waitcnt vmcnt(0)" ::: "memory");
    BAR();
    if (it + 2 < NIT) {
      int sb = (cur >= 1) ? cur - 1 : 2; // (cur+2)%3
      stage(it + 2, sb);
    }
    const unsigned short* Kc = &smem[(part * 3 + cur) * 2048];
    const unsigned short* Vc = &smem[12288 + (part * 3 + cur) * 2048];

    floatx4 s[4][2];
    __builtin_amdgcn_s_setprio(1);
    #pragma unroll
    for (int kt = 0; kt < 2; ++kt) {
      short8 kb0 = *(const short8*)&Kc[(kt * 16 + cl) * 64 + ((quad ^ clm) * 8)];
      short8 kb1 = *(const short8*)&Kc[(kt * 16 + cl) * 64 + (((4 + quad) ^ clm) * 8)];
      #pragma unroll
      for (int qt = 0; qt < 4; ++qt) {
        floatx4 z = {0.f, 0.f, 0.f, 0.f};
        s[qt][kt] = mfma16(kb1, qa[qt][1], mfma16(kb0, qa[qt][0], z));
      }
    }
    __builtin_amdgcn_s_setprio(0);
    #pragma unroll
    for (int qt = 0; qt < 4; ++qt)
      #pragma unroll
      for (int kt = 0; kt < 2; ++kt) {
        unsigned u[4];
        #pragma unroll
        for (int r = 0; r < 4; ++r)
          u[r] = __builtin_bit_cast(unsigned, __builtin_amdgcn_exp2f(s[qt][kt][r]));
        uint2 pk;
        pk.x = __builtin_amdgcn_perm(u[1], u[0], 0x07060302);
        pk.y = __builtin_amdgcn_perm(u[3], u[2], 0x07060302);
        int blk = ((kt * 2 + (quad >> 1)) ^ cl3 ^ cl2) & 3;
        int off = qt * 512 + cl * 32 + blk * 8 + (quad & 1) * 4;
        *(uint2*)(p_w + off) = pk;
      }
    asm volatile("s_waitcnt lgkmcnt(0)" ::: "memory");
    short8 pa[4];
    __builtin_amdgcn_s_setprio(1);
    #pragma unroll
    for (int qt = 0; qt < 4; ++qt) {
      pa[qt] = *(const short8*)(p_w + qt * 512 + cl * 32 + (((quad ^ cl3 ^ cl2) & 3) * 8));
      lacc[qt] = mfma16(ones, pa[qt], lacc[qt]);
    }
    #pragma unroll
    for (int j = 0; j < 4; ++j) {
      short8 vb = *(const short8*)&Vc[(j * 16 + cl) * 32 + (((quad ^ cl3 ^ cl2) & 3) * 8)];
      #pragma unroll
      for (int qt = 0; qt < 4; ++qt)
        oa[qt][j] = mfma16(vb, pa[qt], oa[qt][j]);
    }
    __builtin_amdgcn_s_setprio(0);
    cur = (cur == 2) ? 0 : cur + 1;
  }

  __syncthreads();
  float* red = (float*)smem;
  float* base = red + slice * 4352;
  if (part == 1) {
    #pragma unroll
    for (int qt = 0; qt < 4; ++qt)
      #pragma unroll
      for (int j = 0; j < 4; ++j)
        *(floatx4*)(base + (((qt * 4 + j) * 64 + lane) << 2)) = oa[qt][j];
    #pragma unroll
    for (int qt = 0; qt < 4; ++qt)
      base[4096 + lane * 4 + qt] = lacc[qt][0];
  }
  __syncthreads();
  if (part == 0) {
    #pragma unroll
    for (int qt = 0; qt < 4; ++qt)
      #pragma unroll
      for (int j = 0; j < 4; ++j)
        oa[qt][j] += *(const floatx4*)(base + (((qt * 4 + j) * 64 + lane) << 2));
    float lsum[4];
    #pragma unroll
    for (int qt = 0; qt < 4; ++qt)
      lsum[qt] = lacc[qt][0] + base[4096 + lane * 4 + qt];
    #pragma unroll
    for (int qt = 0; qt < 4; ++qt) {
      float inv = 1.0f / lsum[qt];
      unsigned short* aop = AO + (bz * SS + q0 + qt * 16 + cl) * DM + h * KS + quad * 4;
      #pragma unroll
      for (int j = 0; j < 4; ++j) {
        unsigned short b0 = f2b(oa[qt][j][0] * inv), b1 = f2b(oa[qt][j][1] * inv);
        unsigned short b2 = f2b(oa[qt][j][2] * inv), b3 = f2b(oa[qt][j][3] * inv);
        uint2 pk;
        pk.x = (unsigned)b0 | ((unsigned)b1 << 16);
        pk.y = (unsigned)b2 | ((unsigned)b3 << 16);
        *(uint2*)(aop + j * 16) = pk;
      }
    }
  }
}

// ---- output GEMM: 128x128 tile, 8 waves, BK=32 dbuf, grid 256 (R28) ----
__global__ __launch_bounds__(512) void gemm_out_kernel(
    const unsigned short* __restrict__ ao, const unsigned short* __restrict__ wot,
    const float* __restrict__ bo, float* __restrict__ out) {
  __shared__ __align__(16) unsigned short smem[16384]; // A [2][4096] | B @8192 [2][4096]
  // id&7 = n-panel (XCD class): B-panel 256KB L2-hot across its 32 m-tiles.
  int id = blockIdx.x;
  int m0 = (id >> 3) * 128, n0 = (id & 7) * 128;
  int t = threadIdx.x, w = t >> 6, lane = t & 63, cl = lane & 15, quad = lane >> 4;
  int wr = (w >> 2) * 64, wc = (w & 3) * 32;
  int srow = t >> 2, scol = (t & 3) ^ (srow & 3);
  floatx4 acc[4][2];
  #pragma unroll
  for (int i = 0; i < 4; ++i)
    #pragma unroll
    for (int j = 0; j < 2; ++j)
      acc[i][j] = floatx4{0.f, 0.f, 0.f, 0.f};

  auto stage = [&](int kc, int buf) {
    async16(ao + (m0 + srow) * HKD + kc * 32 + scol * 8, &smem[buf * 4096 + t * 8]);
    async16(wot + (n0 + srow) * HKD + kc * 32 + scol * 8, &smem[8192 + buf * 4096 + t * 8]);
  };
  stage(0, 0);
  stage(1, 1);

  for (int kc = 0; kc < HKD / 32; ++kc) {
    int cur = kc & 1;
    if (kc < HKD / 32 - 1) asm volatile("s_waitcnt vmcnt(2)" ::: "memory");
    else                   asm volatile("s_waitcnt vmcnt(0)" ::: "memory");
    BAR();
    const unsigned short* Ac = &smem[cur * 4096];
    const unsigned short* Bc = &smem[8192 + cur * 4096];
    short8 a[4], b[2];
    #pragma unroll
    for (int i = 0; i < 4; ++i)
      a[i] = *(const short8*)&Ac[(wr + i * 16 + cl) * 32 + ((quad ^ (cl & 3)) * 8)];
    #pragma unroll
    for (int j = 0; j < 2; ++j)
      b[j] = *(const short8*)&Bc[(wc + j * 16 + cl) * 32 + ((quad ^ (cl & 3)) * 8)];
    #pragma unroll
    for (int i = 0; i < 4; ++i)
      #pragma unroll
      for (int j = 0; j < 2; ++j)
        acc[i][j] = mfma16(a[i], b[j], acc[i][j]);
    BAR();
    if (kc + 2 < HKD / 32) stage(kc + 2, cur);
  }
  #pragma unroll
  for (int j = 0; j < 2; ++j) {
    float bj = bo[n0 + wc + j * 16 + cl];
    #pragma unroll
    for (int i = 0; i < 4; ++i)
      #pragma unroll
      for (int r = 0; r < 4; ++r) {
        int token = m0 + wr + i * 16 + quad * 4 + r;
        out[token * DM + n0 + wc + j * 16 + cl] = acc[i][j][r] + bj;
      }
  }
}

extern "C" void kernel_launch(void* const* d_in, const int* in_sizes, int n_in,
                              void* d_out, int out_size, void* d_ws, size_t ws_size,
                              hipStream_t stream) {
  const float* x  = (const float*)d_in[0];
  const float* Wq = (const float*)d_in[1];
  const float* bq = (const float*)d_in[2];
  const float* Wk = (const float*)d_in[3];
  const float* bk = (const float*)d_in[4];
  const float* Wv = (const float*)d_in[5];
  const float* bv = (const float*)d_in[6];
  const float* Wo = (const float*)d_in[7];
  const float* bo = (const float*)d_in[8];
  float* out = (float*)d_out;
  char* ws = (char*)d_ws;
  unsigned short* xb  = (unsigned short*)(ws);                       // 8 MiB
  unsigned short* wqt = (unsigned short*)(ws + (8ull  << 20));       // 2 MiB
  unsigned short* wkt = (unsigned short*)(ws + (10ull << 20));       // 2 MiB
  unsigned short* wvt = (unsigned short*)(ws + (12ull << 20));       // 2 MiB
  unsigned short* wot = (unsigned short*)(ws + (14ull << 20));       // 2 MiB
  unsigned short* qb  = (unsigned short*)(ws + (16ull << 20));       // 8 MiB
  unsigned short* kbf = (unsigned short*)(ws + (24ull << 20));       // 8 MiB
  unsigned short* vt  = (unsigned short*)(ws + (40ull << 20));       // 8 MiB
  unsigned short* ao  = (unsigned short*)(ws + (48ull << 20));       // 8 MiB

  hipLaunchKernelGGL(prep_kernel, dim3(NT * DM / 1024 + 1024), dim3(256), 0, stream,
                     x, Wq, Wk, Wv, Wo, xb, wqt, wkt, wvt, wot);
  hipLaunchKernelGGL(gemm_qkv_kernel, dim3(384), dim3(512), 0, stream,
                     xb, wqt, wkt, wvt, bq, bk, bv, qb, kbf, vt);
  hipLaunchKernelGGL(attn_kernel, dim3(SS / 256, NH, BB), dim3(512), 0, stream, qb, kbf, vt, ao);
  hipLaunchKernelGGL(gemm_out_kernel, dim3(256), dim3(512), 0, stream, ao, wot, bo, out);
}

// Round 18
// 184.286 us; speedup vs baseline: 1.0397x; 1.0019x over previous
//
#include <hip/hip_runtime.h>

// MHA forward, B=2, S=2048, D=1024, H=16, K=64, fp32 in/out, bf16 MFMA internally.
// R30 = exact R28 (best measured: 184.6us, passed) — FINAL. R29's 128x128 qkv
// re-tile failed correctness (absmax 1.0e-2, suspected V-epilogue LDS subtlety);
// reverted to the proven 256x128 qkv. Session: 197.7 -> 184.6us via (1) qkv
// 256x128 z-colocated re-tile, (2) gemm_out 128x128 full-chip re-tile, (3) attn
// XCD head-colocation swizzle (FETCH 69.7->12.35MB). attn 2-phase scaffold
// measured saturated across 8 structural variants (R14-R26).

#define NH 16
#define KS 64
#define DM 1024
#define BB 2
#define SS 2048
#define NT (BB*SS)   // 4096 tokens
#define HKD 1024     // NH*KS
#define L2E 1.44269504088896340736f

typedef __attribute__((ext_vector_type(4))) float floatx4;
typedef __attribute__((ext_vector_type(8))) short short8;

#define BAR() asm volatile("s_barrier" ::: "memory")

__device__ __forceinline__ unsigned short f2b(float f) {
  unsigned u = __builtin_bit_cast(unsigned, f);
  u = (u + 0x7fffu + ((u >> 16) & 1u)) >> 16;
  return (unsigned short)u;
}

__device__ __forceinline__ floatx4 mfma16(short8 a, short8 b, floatx4 c) {
  return __builtin_amdgcn_mfma_f32_16x16x32_bf16(a, b, c, 0, 0, 0);
}

// async global->LDS, 16B per lane. LDS dest must be wave-uniform base + lane*16.
__device__ __forceinline__ void async16(const void* g, void* l) {
  __builtin_amdgcn_global_load_lds(
      (const __attribute__((address_space(1))) unsigned int*)g,
      (__attribute__((address_space(3))) unsigned int*)l, 16, 0, 0);
}

// ------ prep: cast x (f32->bf16) + transpose+cast all W, one launch ------
__global__ __launch_bounds__(256) void prep_kernel(
    const float* __restrict__ x,
    const float* __restrict__ Wq, const float* __restrict__ Wk,
    const float* __restrict__ Wv, const float* __restrict__ Wo,
    unsigned short* __restrict__ xb,
    unsigned short* __restrict__ wqt, unsigned short* __restrict__ wkt,
    unsigned short* __restrict__ wvt, unsigned short* __restrict__ wot) {
  int bid = blockIdx.x;
  if (bid < NT * DM / 1024) {
    int i = (bid * 256 + threadIdx.x) * 4;
    float4 v = *(const float4*)(x + i);
    ushort4 o;
    o.x = f2b(v.x); o.y = f2b(v.y); o.z = f2b(v.z); o.w = f2b(v.w);
    *(ushort4*)(xb + i) = o;
    return;
  }
  int b2 = bid - NT * DM / 1024;
  int z = b2 >> 8;
  const float* W; unsigned short* Wt;
  if (z == 0)      { W = Wq; Wt = wqt; }
  else if (z == 1) { W = Wk; Wt = wkt; }
  else if (z == 2) { W = Wv; Wt = wvt; }
  else             { W = Wo; Wt = wot; }
  __shared__ __align__(16) unsigned short tile[64][80];
  int k0 = (b2 & 15) * 64, n0 = ((b2 >> 4) & 15) * 64;
  int t = threadIdx.x;
  int c0 = (t & 15) * 4, r = t >> 4;
  #pragma unroll
  for (int p = 0; p < 4; ++p) {
    int rr = r + p * 16;
    float4 v = *(const float4*)(W + (k0 + rr) * DM + n0 + c0);
    tile[c0 + 0][rr] = f2b(v.x);
    tile[c0 + 1][rr] = f2b(v.y);
    tile[c0 + 2][rr] = f2b(v.z);
    tile[c0 + 3][rr] = f2b(v.w);
  }
  __syncthreads();
  int cc0 = (t & 7) * 8, rn = t >> 3;
  #pragma unroll
  for (int p = 0; p < 2; ++p) {
    int nn = rn + p * 32;
    *(short8*)(Wt + (n0 + nn) * DM + k0 + cc0) = *(const short8*)(&tile[nn][cc0]);
  }
}

// ---- QKV GEMM: 256x128 tile, 8 waves, BK=32 dbuf + vmcnt(3) prefetch (R21) ----
__global__ __launch_bounds__(512) void gemm_qkv_kernel(
    const unsigned short* __restrict__ xb,
    const unsigned short* __restrict__ wqt, const unsigned short* __restrict__ wkt,
    const unsigned short* __restrict__ wvt,
    const float* __restrict__ bq, const float* __restrict__ bk, const float* __restrict__ bv,
    unsigned short* __restrict__ qb, unsigned short* __restrict__ kbuf,
    unsigned short* __restrict__ vt) {
  __shared__ __align__(16) unsigned short smem[24576]; // A [2][8192] | B @16384 [2][4096]
  // id = y + 8*(z + 3*x): y = XCD/B-panel class, z fastest within x -> A L2-hot x3
  int id = blockIdx.x;
  int y = id & 7, r2 = id >> 3;
  int zid = r2 % 3, xm = r2 / 3;
  const unsigned short* Bt; const float* bias; float scale;
  if (zid == 0)      { Bt = wqt; bias = bq; scale = 0.125f * L2E; }
  else if (zid == 1) { Bt = wkt; bias = bk; scale = 1.0f; }
  else               { Bt = wvt; bias = bv; scale = 1.0f; }
  int m0 = xm * 256, n0 = y * 128;
  int t = threadIdx.x, w = t >> 6, lane = t & 63, cl = lane & 15, quad = lane >> 4;
  int wr = (w >> 1) * 64, wc = (w & 1) * 64;
  floatx4 acc[4][4];
  #pragma unroll
  for (int i = 0; i < 4; ++i)
    #pragma unroll
    for (int j = 0; j < 4; ++j)
      acc[i][j] = floatx4{0.f, 0.f, 0.f, 0.f};

  auto stage = [&](int kc, int buf) {
    #pragma unroll
    for (int i = 0; i < 2; ++i) {
      int c = i * 512 + t;
      int row = c >> 2, col = (c & 3) ^ (row & 3);
      async16(xb + (m0 + row) * DM + kc * 32 + col * 8, &smem[buf * 8192 + c * 8]);
    }
    {
      int c = t;
      int row = c >> 2, col = (c & 3) ^ (row & 3);
      async16(Bt + (n0 + row) * DM + kc * 32 + col * 8, &smem[16384 + buf * 4096 + c * 8]);
    }
  };
  stage(0, 0);
  stage(1, 1);

  for (int kc = 0; kc < DM / 32; ++kc) {
    int cur = kc & 1;
    if (kc < DM / 32 - 1) asm volatile("s_waitcnt vmcnt(3)" ::: "memory");
    else                  asm volatile("s_waitcnt vmcnt(0)" ::: "memory");
    BAR();
    const unsigned short* Ac = &smem[cur * 8192];
    const unsigned short* Bc = &smem[16384 + cur * 4096];
    short8 a[4], b[4];
    #pragma unroll
    for (int i = 0; i < 4; ++i)
      a[i] = *(const short8*)&Ac[(wr + i * 16 + cl) * 32 + ((quad ^ (cl & 3)) * 8)];
    #pragma unroll
    for (int j = 0; j < 4; ++j)
      b[j] = *(const short8*)&Bc[(wc + j * 16 + cl) * 32 + ((quad ^ (cl & 3)) * 8)];
    #pragma unroll
    for (int i = 0; i < 4; ++i)
      #pragma unroll
      for (int j = 0; j < 4; ++j)
        acc[i][j] = mfma16(a[i], b[j], acc[i][j]);
    BAR();
    if (kc + 2 < DM / 32) stage(kc + 2, cur);
  }
  __syncthreads();

  int h = (n0 + wc) >> 6;
  if (zid < 2) {
    unsigned short* dst = (zid == 0) ? qb : kbuf;
    #pragma unroll
    for (int j = 0; j < 4; ++j) {
      float bj = bias[n0 + wc + j * 16 + cl];
      int kd = j * 16 + cl;
      #pragma unroll
      for (int i = 0; i < 4; ++i)
        #pragma unroll
        for (int r = 0; r < 4; ++r) {
          int token = m0 + wr + i * 16 + quad * 4 + r;
          int bz = token >> 11, s = token & (SS - 1);
          float val = (acc[i][j][r] + bj) * scale;
          dst[(((bz * NH + h) * SS + s) << 6) + kd] = f2b(val);
        }
    }
  } else {
    // V: transpose via per-wave LDS region, two rounds of 32 kd (8x2304 <= 24576)
    unsigned short* tr = &smem[w * 2304];
    int tokbase = m0 + wr;
    int bz = tokbase >> 11, s0 = tokbase & (SS - 1);
    unsigned short* vdst = vt + (((bz * NH + h) * KS) * SS) + s0;
    #pragma unroll
    for (int jr = 0; jr < 2; ++jr) {
      #pragma unroll
      for (int jj = 0; jj < 2; ++jj) {
        int j = jr * 2 + jj;
        float bj = bias[n0 + wc + j * 16 + cl];
        #pragma unroll
        for (int i = 0; i < 4; ++i) {
          unsigned short b0 = f2b(acc[i][j][0] + bj), b1 = f2b(acc[i][j][1] + bj);
          unsigned short b2 = f2b(acc[i][j][2] + bj), b3 = f2b(acc[i][j][3] + bj);
          uint2 pk;
          pk.x = (unsigned)b0 | ((unsigned)b1 << 16);
          pk.y = (unsigned)b2 | ((unsigned)b3 << 16);
          *(uint2*)&tr[(jj * 16 + cl) * 72 + i * 16 + quad * 4] = pk;
        }
      }
      asm volatile("s_waitcnt lgkmcnt(0)" ::: "memory");
      #pragma unroll
      for (int p = 0; p < 4; ++p) {
        int row = p * 8 + (lane >> 3);
        int tk = (lane & 7) * 8;
        short8 vv = *(const short8*)&tr[row * 72 + tk];
        *(short8*)(vdst + (jr * 32 + row) * SS + tk) = vv;
      }
      asm volatile("s_waitcnt lgkmcnt(0)" ::: "memory");
    }
  }
}

// ---- attention: R17 verbatim — split-K-2 dual-stream, 8 waves x 64 q-rows ----
__global__ __launch_bounds__(512) void attn_kernel(
    const unsigned short* __restrict__ Q, const unsigned short* __restrict__ Kb,
    const unsigned short* __restrict__ Vt, unsigned short* __restrict__ AO) {
  __shared__ __align__(16) unsigned short smem[40960];
  int t = threadIdx.x, w = t >> 6, lane = t & 63, cl = lane & 15, quad = lane >> 4;
  int clm = cl & 7, cl3 = cl & 3, cl2 = cl >> 2;
  int id = blockIdx.x + (SS / 256) * (blockIdx.y + NH * blockIdx.z);
  int c = id & 7, k = id >> 3;
  int head_lin = c + 8 * (k & 3);
  int qx = k >> 2;
  int h = head_lin & (NH - 1), bz = head_lin >> 4;
  int bh = bz * NH + h;
  int slice = w & 3, part = w >> 2;
  int q0 = qx * 256 + slice * 64;
  const unsigned short* Qp = Q + (bh * SS + q0) * KS;
  const unsigned short* Kp = Kb + bh * SS * KS;
  const unsigned short* Vp = Vt + bh * KS * SS;
  unsigned short* p_w = smem + 24576 + w * 2048;

  short8 qa[4][2];
  #pragma unroll
  for (int qt = 0; qt < 4; ++qt)
    #pragma unroll
    for (int cc = 0; cc < 2; ++cc)
      qa[qt][cc] = *(const short8*)(Qp + (qt * 16 + cl) * KS + cc * 32 + quad * 8);

  short8 ones;
  #pragma unroll
  for (int j = 0; j < 8; ++j) ones[j] = (short)0x3f80; // bf16 1.0

  floatx4 lacc[4];
  floatx4 oa[4][4];
  #pragma unroll
  for (int qt = 0; qt < 4; ++qt) {
    lacc[qt] = floatx4{0.f, 0.f, 0.f, 0.f};
    #pragma unroll
    for (int j = 0; j < 4; ++j) oa[qt][j] = floatx4{0.f, 0.f, 0.f, 0.f};
  }

  int st = t >> 8, lt = t & 255;
  int krow = lt >> 3, kcol = (lt & 7) ^ (krow & 7);
  int vd = lt >> 2, vcol = ((lt & 3) ^ (vd & 3) ^ ((vd >> 2) & 3)) & 3;
  auto stage = [&](int it, int buf) {
    async16(Kp + (st * 1024 + it * 32 + krow) * KS + kcol * 8,
            &smem[(st * 3 + buf) * 2048 + lt * 8]);
    async16(Vp + vd * SS + st * 1024 + it * 32 + vcol * 8,
            &smem[12288 + (st * 3 + buf) * 2048 + lt * 8]);
  };
  stage(0, 0);
  stage(1, 1);

  const int NIT = 1024 / 32;
  int cur = 0;
  for (int it = 0; it < NIT; ++it) {
    if (it < NIT - 1) asm volatile("s_waitcnt vmcnt(2)" ::: "memory");
    else              asm volatile("s_waitcnt vmcnt(0)" ::: "memory");
    BAR();
    if (it + 2 < NIT) {
      int sb = (cur >= 1) ? cur - 1 : 2; // (cur+2)%3
      stage(it + 2, sb);
    }
    const unsigned short* Kc = &smem[(part * 3 + cur) * 2048];
    const unsigned short* Vc = &smem[12288 + (part * 3 + cur) * 2048];

    floatx4 s[4][2];
    __builtin_amdgcn_s_setprio(1);
    #pragma unroll
    for (int kt = 0; kt < 2; ++kt) {
      short8 kb0 = *(const short8*)&Kc[(kt * 16 + cl) * 64 + ((quad ^ clm) * 8)];
      short8 kb1 = *(const short8*)&Kc[(kt * 16 + cl) * 64 + (((4 + quad) ^ clm) * 8)];
      #pragma unroll
      for (int qt = 0; qt < 4; ++qt) {
        floatx4 z = {0.f, 0.f, 0.f, 0.f};
        s[qt][kt] = mfma16(kb1, qa[qt][1], mfma16(kb0, qa[qt][0], z));
      }
    }
    __builtin_amdgcn_s_setprio(0);
    #pragma unroll
    for (int qt = 0; qt < 4; ++qt)
      #pragma unroll
      for (int kt = 0; kt < 2; ++kt) {
        unsigned u[4];
        #pragma unroll
        for (int r = 0; r < 4; ++r)
          u[r] = __builtin_bit_cast(unsigned, __builtin_amdgcn_exp2f(s[qt][kt][r]));
        uint2 pk;
        pk.x = __builtin_amdgcn_perm(u[1], u[0], 0x07060302);
        pk.y = __builtin_amdgcn_perm(u[3], u[2], 0x07060302);
        int blk = ((kt * 2 + (quad >> 1)) ^ cl3 ^ cl2) & 3;
        int off = qt * 512 + cl * 32 + blk * 8 + (quad & 1) * 4;
        *(uint2*)(p_w + off) = pk;
      }
    asm volatile("s_waitcnt lgkmcnt(0)" ::: "memory");
    short8 pa[4];
    __builtin_amdgcn_s_setprio(1);
    #pragma unroll
    for (int qt = 0; qt < 4; ++qt) {
      pa[qt] = *(const short8*)(p_w + qt * 512 + cl * 32 + (((quad ^ cl3 ^ cl2) & 3) * 8));
      lacc[qt] = mfma16(ones, pa[qt], lacc[qt]);
    }
    #pragma unroll
    for (int j = 0; j < 4; ++j) {
      short8 vb = *(const short8*)&Vc[(j * 16 + cl) * 32 + (((quad ^ cl3 ^ cl2) & 3) * 8)];
      #pragma unroll
      for (int qt = 0; qt < 4; ++qt)
        oa[qt][j] = mfma16(vb, pa[qt], oa[qt][j]);
    }
    __builtin_amdgcn_s_setprio(0);
    cur = (cur == 2) ? 0 : cur + 1;
  }

  __syncthreads();
  float* red = (float*)smem;
  float* base = red + slice * 4352;
  if (part == 1) {
    #pragma unroll
    for (int qt = 0; qt < 4; ++qt)
      #pragma unroll
      for (int j = 0; j < 4; ++j)
        *(floatx4*)(base + (((qt * 4 + j) * 64 + lane) << 2)) = oa[qt][j];
    #pragma unroll
    for (int qt = 0; qt < 4; ++qt)
      base[4096 + lane * 4 + qt] = lacc[qt][0];
  }
  __syncthreads();
  if (part == 0) {
    #pragma unroll
    for (int qt = 0; qt < 4; ++qt)
      #pragma unroll
      for (int j = 0; j < 4; ++j)
        oa[qt][j] += *(const floatx4*)(base + (((qt * 4 + j) * 64 + lane) << 2));
    float lsum[4];
    #pragma unroll
    for (int qt = 0; qt < 4; ++qt)
      lsum[qt] = lacc[qt][0] + base[4096 + lane * 4 + qt];
    #pragma unroll
    for (int qt = 0; qt < 4; ++qt) {
      float inv = 1.0f / lsum[qt];
      unsigned short* aop = AO + (bz * SS + q0 + qt * 16 + cl) * DM + h * KS + quad * 4;
      #pragma unroll
      for (int j = 0; j < 4; ++j) {
        unsigned short b0 = f2b(oa[qt][j][0] * inv), b1 = f2b(oa[qt][j][1] * inv);
        unsigned short b2 = f2b(oa[qt][j][2] * inv), b3 = f2b(oa[qt][j][3] * inv);
        uint2 pk;
        pk.x = (unsigned)b0 | ((unsigned)b1 << 16);
        pk.y = (unsigned)b2 | ((unsigned)b3 << 16);
        *(uint2*)(aop + j * 16) = pk;
      }
    }
  }
}

// ---- output GEMM: 128x128 tile, 8 waves, BK=32 dbuf, grid 256 (R28) ----
__global__ __launch_bounds__(512) void gemm_out_kernel(
    const unsigned short* __restrict__ ao, const unsigned short* __restrict__ wot,
    const float* __restrict__ bo, float* __restrict__ out) {
  __shared__ __align__(16) unsigned short smem[16384]; // A [2][4096] | B @8192 [2][4096]
  // id&7 = n-panel (XCD class): B-panel 256KB L2-hot across its 32 m-tiles.
  int id = blockIdx.x;
  int m0 = (id >> 3) * 128, n0 = (id & 7) * 128;
  int t = threadIdx.x, w = t >> 6, lane = t & 63, cl = lane & 15, quad = lane >> 4;
  int wr = (w >> 2) * 64, wc = (w & 3) * 32;
  int srow = t >> 2, scol = (t & 3) ^ (srow & 3);
  floatx4 acc[4][2];
  #pragma unroll
  for (int i = 0; i < 4; ++i)
    #pragma unroll
    for (int j = 0; j < 2; ++j)
      acc[i][j] = floatx4{0.f, 0.f, 0.f, 0.f};

  auto stage = [&](int kc, int buf) {
    async16(ao + (m0 + srow) * HKD + kc * 32 + scol * 8, &smem[buf * 4096 + t * 8]);
    async16(wot + (n0 + srow) * HKD + kc * 32 + scol * 8, &smem[8192 + buf * 4096 + t * 8]);
  };
  stage(0, 0);
  stage(1, 1);

  for (int kc = 0; kc < HKD / 32; ++kc) {
    int cur = kc & 1;
    if (kc < HKD / 32 - 1) asm volatile("s_waitcnt vmcnt(2)" ::: "memory");
    else                   asm volatile("s_waitcnt vmcnt(0)" ::: "memory");
    BAR();
    const unsigned short* Ac = &smem[cur * 4096];
    const unsigned short* Bc = &smem[8192 + cur * 4096];
    short8 a[4], b[2];
    #pragma unroll
    for (int i = 0; i < 4; ++i)
      a[i] = *(const short8*)&Ac[(wr + i * 16 + cl) * 32 + ((quad ^ (cl & 3)) * 8)];
    #pragma unroll
    for (int j = 0; j < 2; ++j)
      b[j] = *(const short8*)&Bc[(wc + j * 16 + cl) * 32 + ((quad ^ (cl & 3)) * 8)];
    #pragma unroll
    for (int i = 0; i < 4; ++i)
      #pragma unroll
      for (int j = 0; j < 2; ++j)
        acc[i][j] = mfma16(a[i], b[j], acc[i][j]);
    BAR();
    if (kc + 2 < HKD / 32) stage(kc + 2, cur);
  }
  #pragma unroll
  for (int j = 0; j < 2; ++j) {
    float bj = bo[n0 + wc + j * 16 + cl];
    #pragma unroll
    for (int i = 0; i < 4; ++i)
      #pragma unroll
      for (int r = 0; r < 4; ++r) {
        int token = m0 + wr + i * 16 + quad * 4 + r;
        out[token * DM + n0 + wc + j * 16 + cl] = acc[i][j][r] + bj;
      }
  }
}

extern "C" void kernel_launch(void* const* d_in, const int* in_sizes, int n_in,
                              void* d_out, int out_size, void* d_ws, size_t ws_size,
                              hipStream_t stream) {
  const float* x  = (const float*)d_in[0];
  const float* Wq = (const float*)d_in[1];
  const float* bq = (const float*)d_in[2];
  const float* Wk = (const float*)d_in[3];
  const float* bk = (const float*)d_in[4];
  const float* Wv = (const float*)d_in[5];
  const float* bv = (const float*)d_in[6];
  const float* Wo = (const float*)d_in[7];
  const float* bo = (const float*)d_in[8];
  float* out = (float*)d_out;
  char* ws = (char*)d_ws;
  unsigned short* xb  = (unsigned short*)(ws);                       // 8 MiB
  unsigned short* wqt = (unsigned short*)(ws + (8ull  << 20));       // 2 MiB
  unsigned short* wkt = (unsigned short*)(ws + (10ull << 20));       // 2 MiB
  unsigned short* wvt = (unsigned short*)(ws + (12ull << 20));       // 2 MiB
  unsigned short* wot = (unsigned short*)(ws + (14ull << 20));       // 2 MiB
  unsigned short* qb  = (unsigned short*)(ws + (16ull << 20));       // 8 MiB
  unsigned short* kbf = (unsigned short*)(ws + (24ull << 20));       // 8 MiB
  unsigned short* vt  = (unsigned short*)(ws + (40ull << 20));       // 8 MiB
  unsigned short* ao  = (unsigned short*)(ws + (48ull << 20));       // 8 MiB

  hipLaunchKernelGGL(prep_kernel, dim3(NT * DM / 1024 + 1024), dim3(256), 0, stream,
                     x, Wq, Wk, Wv, Wo, xb, wqt, wkt, wvt, wot);
  hipLaunchKernelGGL(gemm_qkv_kernel, dim3(384), dim3(512), 0, stream,
                     xb, wqt, wkt, wvt, bq, bk, bv, qb, kbf, vt);
  hipLaunchKernelGGL(attn_kernel, dim3(SS / 256, NH, BB), dim3(512), 0, stream, qb, kbf, vt, ao);
  hipLaunchKernelGGL(gemm_out_kernel, dim3(256), dim3(512), 0, stream, ao, wot, bo, out);
}